// Round 9
// baseline (327.098 us; speedup 1.0000x reference)
//
#include <hip/hip_runtime.h>

constexpr int K = 1024;        // num codes
constexpr int D = 64;          // dim
constexpr int N = 131072;      // 32*4096 points
constexpr float INV_N = 1.0f / 131072.0f;
constexpr float INV_ELEMS = 1.0f / 8388608.0f;  // N*D
constexpr float LOG2E = 1.4426950408889634f;
constexpr float DELTA = 0.0072f;  // refine margin in log2e-scaled units

// Output layout (flat float32, return order)
constexpr size_t O_QST  = 0;          // [N*D] quantized_st
constexpr size_t O_LOSS = 8388608;    // [1]
constexpr size_t O_IDX  = 8388609;    // [N]
constexpr size_t O_CBL  = 8519681;    // [1]
constexpr size_t O_CML  = 8519682;    // [1]
constexpr size_t O_PPL  = 8519683;    // [1]
constexpr size_t O_USG  = 8519684;    // [1024]
constexpr size_t O_SU   = 8520708;    // [1024]

// Workspace (float offsets):
//  [0,1024)       cn    raw fp32 codebook norms (rescan exact pass)
//  [1024,2048)    counts
//  [2048,3072)    susum
//  [3072,3328)    sqp
//  [3328,4352)    cn2f  cn * log2e (fp32, acc-init)
//  [4352,37120)   chA   bf16 hi split of codebook*log2e, frag layout
//  [37120,69888)  clA   bf16 lo split
//  [69888,200960) ctA   per-point ct2 = m - log2(Z)
//  [200960,332032) worklist: [0]=int count, [1..]=int point ids (cap 131071)

// qst slots double as z-frag storage between p1 and epi:
// tile t (32 points): shorts base = t*4096; hi frag at (ks*64+lane)*8,
// lo frag at 2048 + (ks*64+lane)*8.  Element (point=lane&31,
// dim=16*ks+(lane>>5)*8+j) holds split of (-2*z).

typedef __attribute__((ext_vector_type(8))) short bf16x8;
typedef __attribute__((ext_vector_type(16))) float f32x16;
typedef __attribute__((ext_vector_type(4))) float f32x4;  // nontemporal-ok

__device__ inline unsigned short f2bf(float f) {  // RTNE fp32->bf16
  unsigned u = __float_as_uint(f);
  return (unsigned short)((u + 0x7FFF + ((u >> 16) & 1)) >> 16);
}
__device__ inline float bf2f(unsigned short h) {
  return __uint_as_float(((unsigned)h) << 16);
}
__device__ inline float fexp2(float x) {  // raw v_exp_f32 (args <= 0 here)
  return __builtin_amdgcn_exp2f(x);
}
__device__ inline float fmed3(float a, float b, float c) {
  return __builtin_amdgcn_fmed3f(a, b, c);
}
__device__ inline bf16x8 negbf8(bf16x8 v) {  // flip sign of 8 packed bf16
  union { bf16x8 s; uint4 u; } x;
  x.s = v;
  x.u.x ^= 0x80008000u; x.u.y ^= 0x80008000u;
  x.u.z ^= 0x80008000u; x.u.w ^= 0x80008000u;
  return x.s;
}

// ---------------------------------------------------------------------------
// Codebook*log2e -> bf16 hi/lo frags + raw & scaled norms.
// Each 64-thread wave owns exactly one code row (gid>>6 uniform per wave).
__global__ __launch_bounds__(256) void vq_prep(const float* __restrict__ cb,
                                               short* __restrict__ chA,
                                               short* __restrict__ clA,
                                               float* __restrict__ cn,
                                               float* __restrict__ cn2f) {
  const int gid = blockIdx.x * 256 + threadIdx.x;  // 65536
  const int c = gid >> 6, d = gid & 63;
  float raw = cb[gid];
  float v = raw * LOG2E;
  unsigned short h = f2bf(v);
  unsigned short l = f2bf(v - bf2f(h));
  const int tile = c >> 5, ks = d >> 4, hff = (d >> 3) & 1, j = d & 7;
  const int lane = hff * 32 + (c & 31);
  const size_t off = ((size_t)((tile * 4 + ks) * 64 + lane)) * 8 + j;
  chA[off] = (short)h;
  clA[off] = (short)l;
  // norm reduction across the wave (one code per wave)
  float s = raw * raw;
#pragma unroll
  for (int o = 32; o > 0; o >>= 1) s += __shfl_xor(s, o, 64);
  if (d == 0) {
    cn[c] = s;
    cn2f[c] = s * LOG2E;
  }
}

// ---------------------------------------------------------------------------
// Pass 1, split-K: 8-wave blocks; wave pair shares a 32-point tile, each wave
// covers 512 codes (16 tiles).  Partials merge through LDS.  Grid stays 1024
// blocks -> 32 waves/CU (was 16): doubles occupancy to hide exp2/waitcnt
// stalls (r7: grid-limited at 4 waves/SIMD, both pipes only 77% covered).
// Single 12-deep MFMA acc chain, med3 (min,secmin) tree, no per-point atomics.
__global__ __launch_bounds__(512, 8) void vq_p1(
    const float* __restrict__ z, const short* __restrict__ chA,
    const short* __restrict__ clA, const float* __restrict__ cn2f,
    float* __restrict__ out, float* __restrict__ ctA,
    int* __restrict__ wl) {
  __shared__ float Lm[8][32], LZ[8][32], Lb2[8][32];
  __shared__ int Lbi[8][32];
  const int tid = threadIdx.x;
  const int lane = tid & 63;
  const int w = tid >> 6;        // 0..7
  const int pair = w >> 1;       // 0..3: point tile within block
  const int half = w & 1;        // 0: codes 0-511, 1: codes 512-1023
  const int W = blockIdx.x * 4 + pair;
  const int i0 = W * 32;
  const int col = lane & 31;
  const int hf = lane >> 5;

  // convert this tile's z -> -2z hi/lo frags (both waves of the pair compute;
  // z rows are L1/L2-shared).  Only half==0 stores them for p2.
  bf16x8 zh[4], zl[4];
  const float* zr = z + (size_t)(i0 + col) * 64 + hf * 8;
#pragma unroll
  for (int ks = 0; ks < 4; ks++) {
    float4 a = *(const float4*)(zr + ks * 16);
    float4 b = *(const float4*)(zr + ks * 16 + 4);
    float vv[8] = {a.x, a.y, a.z, a.w, b.x, b.y, b.z, b.w};
#pragma unroll
    for (int j = 0; j < 8; j++) {
      float vm = -2.0f * vv[j];
      unsigned short h = f2bf(vm);
      zh[ks][j] = (short)h;
      zl[ks][j] = (short)f2bf(vm - bf2f(h));
    }
  }
  if (half == 0) {
    short* base = (short*)out + (size_t)W * 4096;  // O_QST == 0
#pragma unroll
    for (int ks = 0; ks < 4; ks++) {
      *(bf16x8*)(base + (ks * 64 + lane) * 8) = zh[ks];
      *(bf16x8*)(base + 2048 + (ks * 64 + lane) * 8) = zl[ks];
    }
  }

  float b1 = 3.0e38f, b2 = 3.0e38f, Z = 0.0f;
  int bi = 0;

  for (int t = 0; t < 16; t++) {
    const int tt = half * 16 + t;  // this wave's code tile
    // acc init = cn2 of this tile's 16 row-codes (exact fp32 affine)
    float4 cniv[4];
#pragma unroll
    for (int q = 0; q < 4; q++)
      cniv[q] = *(const float4*)(cn2f + tt * 32 + 8 * q + 4 * hf);
    f32x16 acc;
#pragma unroll
    for (int r = 0; r < 16; r++)
      acc[r] = ((const float*)&cniv[r >> 2])[r & 3];
    const short* ch = chA + ((size_t)(tt * 4) * 64 + lane) * 8;
    const short* cl = clA + ((size_t)(tt * 4) * 64 + lane) * 8;
#pragma unroll
    for (int ks = 0; ks < 4; ks++) {
      bf16x8 Ah = *(const bf16x8*)(ch + ks * 512);
      bf16x8 Al = *(const bf16x8*)(cl + ks * 512);
      acc = __builtin_amdgcn_mfma_f32_32x32x16_bf16(Ah, zh[ks], acc, 0, 0, 0);
      acc = __builtin_amdgcn_mfma_f32_32x32x16_bf16(Ah, zl[ks], acc, 0, 0, 0);
      acc = __builtin_amdgcn_mfma_f32_32x32x16_bf16(Al, zh[ks], acc, 0, 0, 0);
    }
    // (min, secmin) merge tree with med3 merges.  Sorted pairs (a1<=a2),
    // (b1<=b2): min = min(a1,b1), sec = med3(a1, b1, min(a2,b2)).
    float pm[8], px[8];
#pragma unroll
    for (int r = 0; r < 8; r++) {
      pm[r] = fminf(acc[2 * r], acc[2 * r + 1]);
      px[r] = fmaxf(acc[2 * r], acc[2 * r + 1]);
    }
    float qm[4], qx[4];
#pragma unroll
    for (int r = 0; r < 4; r++) {
      qm[r] = fminf(pm[2 * r], pm[2 * r + 1]);
      qx[r] = fmed3(pm[2 * r], pm[2 * r + 1], fminf(px[2 * r], px[2 * r + 1]));
    }
    float rm0 = fminf(qm[0], qm[1]);
    float rx0 = fmed3(qm[0], qm[1], fminf(qx[0], qx[1]));
    float rm1 = fminf(qm[2], qm[3]);
    float rx1 = fmed3(qm[2], qm[3], fminf(qx[2], qx[3]));
    float cm = fminf(rm0, rm1);
    float cm2 = fmed3(rm0, rm1, fminf(rx0, rx1));
    // argmin of the tile (equality select; exact ties -> margin 0 -> rescan)
    int ti = 0;
#pragma unroll
    for (int r = 0; r < 16; r++)
      if (acc[r] == cm) ti = tt * 32 + (r & 3) + 8 * (r >> 2) + 4 * hf;
    // fold into running (b1, b2, bi); newm doubles as softmax max
    float newm = fminf(b1, cm);
    b2 = fmed3(b1, cm, fminf(b2, cm2));
    bi = (cm < b1) ? ti : bi;
    float zs = 0.0f;
#pragma unroll
    for (int r = 0; r < 16; r++) zs += fexp2(newm - acc[r]);
    Z = Z * fexp2(newm - b1) + zs;
    b1 = newm;
  }
  // intra-wave merge of the two hf halves
  float m2 = __shfl_xor(b1, 32, 64);
  float Z2 = __shfl_xor(Z, 32, 64);
  float b2o = __shfl_xor(b2, 32, 64);
  int bio = __shfl_xor(bi, 32, 64);
  float Mw = fminf(b1, m2);
  float Zw = Z * fexp2(Mw - b1) + Z2 * fexp2(Mw - m2);
  bool takeh = (m2 < b1) || (m2 == b1 && bio < bi);
  float g2w = fminf(fmaxf(b1, m2), fminf(b2, b2o));
  int biw = takeh ? bio : bi;
  // inter-wave (code-half) merge through LDS
  if (hf == 0) {
    Lm[w][col] = Mw;
    LZ[w][col] = Zw;
    Lb2[w][col] = g2w;
    Lbi[w][col] = biw;
  }
  __syncthreads();
  if (half == 0 && hf == 0) {
    float mB = Lm[w ^ 1][col];
    float ZB = LZ[w ^ 1][col];
    float b2B = Lb2[w ^ 1][col];
    int biB = Lbi[w ^ 1][col];
    float M = fminf(Mw, mB);
    float Zt = Zw * fexp2(M - Mw) + ZB * fexp2(M - mB);
    // strict less: ties keep half 0 (lower code index) -- correct argmin
    int big = (mB < Mw) ? biB : biw;
    float g2 = fminf(fmaxf(Mw, mB), fminf(g2w, b2B));
    ctA[i0 + col] = M - __log2f(Zt);
    out[O_IDX + (size_t)(i0 + col)] = (float)big;
    if (g2 - M < DELTA) {  // runner-up within margin -> exact rescan
      int slot = atomicAdd(wl, 1);
      if (slot < 131071) wl[1 + slot] = i0 + col;
    }
  }
}

// ---------------------------------------------------------------------------
// Histogram of indices via LDS privatization: 64 blocks x 2048 points each.
// 131K LDS atomics + 64K global atomics (vs 131K scattered global atomics).
__global__ __launch_bounds__(256) void vq_count(
    const float* __restrict__ idxF, float* __restrict__ counts) {
  __shared__ int h[K];
  const int tid = threadIdx.x;
#pragma unroll
  for (int k = 0; k < K / 256; k++) h[tid + k * 256] = 0;
  __syncthreads();
  const int base = blockIdx.x * 2048 + tid;
#pragma unroll
  for (int k = 0; k < 8; k++) {
    int c = (int)idxF[base + k * 256];
    atomicAdd(&h[c], 1);
  }
  __syncthreads();
#pragma unroll
  for (int k = 0; k < K / 256; k++) {
    int v = h[tid + k * 256];
    if (v) atomicAdd(&counts[tid + k * 256], (float)v);
  }
}

// ---------------------------------------------------------------------------
// Pass 2: wave = 32 resident (negated) codes, streams prebuilt z A-frags.
// Single MFMA chain; acc init = ct2_i - cn2_j (exact fp32); su += 2^acc.
// 2048 blocks: 256 point-groups x 16 tiles.
__global__ __launch_bounds__(256, 4) void vq_p2(
    const short* __restrict__ zF, const short* __restrict__ chA,
    const short* __restrict__ clA, const float* __restrict__ cn2f,
    const float* __restrict__ ctA, float* __restrict__ susum) {
  const int lane = threadIdx.x & 63;
  const int wv = threadIdx.x >> 6;
  const int b = blockIdx.x;
  // XCD swizzle: all 8 blocks of one point-group on one XCD (L2 reuse)
  const int xcd = b & 7;
  const int sl = b >> 3;                 // 0..255
  const int pg = xcd * 32 + (sl >> 3);   // 0..255 point group (512 points)
  const int g = (sl & 7) * 4 + wv;       // 0..31 code tile
  const int col = lane & 31;
  const int hf = lane >> 5;

  // resident codebook B frags, negated (codebook is +c*log2e; we need -c)
  bf16x8 Bh[4], Bl[4];
  const short* ch = chA + ((size_t)(g * 4) * 64 + lane) * 8;
  const short* cl = clA + ((size_t)(g * 4) * 64 + lane) * 8;
#pragma unroll
  for (int ks = 0; ks < 4; ks++) {
    Bh[ks] = negbf8(*(const bf16x8*)(ch + ks * 512));
    Bl[ks] = negbf8(*(const bf16x8*)(cl + ks * 512));
  }
  const float cnv = cn2f[g * 32 + col];  // this lane's code norm (scaled)

  float su = 0.0f;
  for (int pt = 0; pt < 16; pt++) {
    const int T = pg * 16 + pt;
    const short* base = zF + (size_t)T * 4096;
    float4 ctv[4];
#pragma unroll
    for (int q = 0; q < 4; q++)
      ctv[q] = *(const float4*)(ctA + T * 32 + 8 * q + 4 * hf);
    f32x16 acc;
#pragma unroll
    for (int r = 0; r < 16; r++)
      acc[r] = ((const float*)&ctv[r >> 2])[r & 3] - cnv;
#pragma unroll
    for (int ks = 0; ks < 4; ks++) {
      bf16x8 Ah = *(const bf16x8*)(base + (ks * 64 + lane) * 8);
      bf16x8 Al = *(const bf16x8*)(base + 2048 + (ks * 64 + lane) * 8);
      acc = __builtin_amdgcn_mfma_f32_32x32x16_bf16(Ah, Bh[ks], acc, 0, 0, 0);
      acc = __builtin_amdgcn_mfma_f32_32x32x16_bf16(Ah, Bl[ks], acc, 0, 0, 0);
      acc = __builtin_amdgcn_mfma_f32_32x32x16_bf16(Al, Bh[ks], acc, 0, 0, 0);
    }
#pragma unroll
    for (int r = 0; r < 16; r++) su += fexp2(acc[r]);
  }
  su += __shfl_xor(su, 32, 64);
  if (hf == 0) atomicAdd(&susum[g * 32 + col], su);
}

// ---------------------------------------------------------------------------
// Exact fp32 rescan for flagged (ambiguous) points only. Wave per entry,
// grid-stride over the device worklist. Updates out[O_IDX] and fixes counts.
__global__ __launch_bounds__(256) void vq_rescan(
    const float* __restrict__ z, const float* __restrict__ cb,
    const float* __restrict__ cn, float* __restrict__ out,
    float* __restrict__ counts, const int* __restrict__ wl) {
  const int nr = min(wl[0], 131071);
  const int wv = blockIdx.x * 4 + (threadIdx.x >> 6);
  const int lane = threadIdx.x & 63;
  for (int e = wv; e < nr; e += gridDim.x * 4) {
    const int i = wl[1 + e];
    const float4* zi4 = (const float4*)(z + (size_t)i * 64);
    float4 zq[16];
#pragma unroll
    for (int k = 0; k < 16; k++) zq[k] = zi4[k];
    float best = 3.0e38f;
    int bidx = 0;
    for (int cc = 0; cc < 16; cc++) {
      int c = cc * 64 + lane;
      const float4* cr = (const float4*)(cb + (size_t)c * 64);
      float dot0 = 0.0f, dot1 = 0.0f;
#pragma unroll
      for (int k = 0; k < 16; k += 2) {
        float4 a = cr[k];
        float4 bq = cr[k + 1];
        dot0 += zq[k].x * a.x + zq[k].y * a.y + zq[k].z * a.z + zq[k].w * a.w;
        dot1 += zq[k + 1].x * bq.x + zq[k + 1].y * bq.y + zq[k + 1].z * bq.z +
                zq[k + 1].w * bq.w;
      }
      float s = cn[c] - 2.0f * (dot0 + dot1);
      if (s < best) { best = s; bidx = c; }
    }
#pragma unroll
    for (int o = 32; o > 0; o >>= 1) {
      float ob = __shfl_xor(best, o, 64);
      int oi = __shfl_xor(bidx, o, 64);
      if (ob < best || (ob == best && oi < bidx)) { best = ob; bidx = oi; }
    }
    if (lane == 0) {
      const int old = (int)out[O_IDX + (size_t)i];
      if (bidx != old) {
        out[O_IDX + (size_t)i] = (float)bidx;
        atomicAdd(&counts[old], -1.0f);
        atomicAdd(&counts[bidx], 1.0f);
      }
    }
  }
}

// ---------------------------------------------------------------------------
// Epilogue: 8 independent float4 chunks per thread, loads batch-issued by
// class (idx -> z -> cb) for MLP.  No LDS, no barrier, no per-point atomics:
// per-wave shuffle reduce + one sqp atomic per wave.  Nontemporal stores keep
// the 32 MB qst stream out of L2.
__global__ __launch_bounds__(256) void vq_epi(
    const float* __restrict__ z, const float* __restrict__ cb,
    const float* __restrict__ idxF, float* __restrict__ qst,
    float* __restrict__ sqp) {
  const int tid = threadIdx.x;
  const int base = blockIdx.x * 2048 + tid;  // 8 chunks strided by 256
  const int q = base & 15;                   // dim-chunk, uniform over k
  int bI[8];
#pragma unroll
  for (int k = 0; k < 8; k++) bI[k] = (int)idxF[(base + k * 256) >> 4];
  f32x4 zv[8];
#pragma unroll
  for (int k = 0; k < 8; k++)
    zv[k] = __builtin_nontemporal_load((const f32x4*)z + base + k * 256);
  f32x4 qv[8];
#pragma unroll
  for (int k = 0; k < 8; k++) qv[k] = ((const f32x4*)cb)[bI[k] * 16 + q];
  float sq = 0.0f;
#pragma unroll
  for (int k = 0; k < 8; k++) {
    f32x4 o = zv[k] + (qv[k] - zv[k]);
    __builtin_nontemporal_store(o, (f32x4*)qst + base + k * 256);
    f32x4 e = qv[k] - zv[k];
    sq += e.x * e.x + e.y * e.y + e.z * e.z + e.w * e.w;
  }
#pragma unroll
  for (int o2 = 32; o2 > 0; o2 >>= 1) sq += __shfl_xor(sq, o2, 64);
  if ((tid & 63) == 0)
    atomicAdd(&sqp[(blockIdx.x * 4 + (tid >> 6)) & 255], sq);
}

// ---------------------------------------------------------------------------
__global__ __launch_bounds__(1024) void vq_final(
    const float* __restrict__ counts, const float* __restrict__ susum,
    const float* __restrict__ sqp, float* __restrict__ out) {
  __shared__ float red[16];
  __shared__ float red2[16];
  const int t = threadIdx.x;
  float cnt = counts[t];
  float usage = cnt * INV_N;
  out[O_USG + t] = usage;
  out[O_SU + t] = susum[t] * INV_N;
  float term = usage * logf(usage + 1e-8f);
  float sq = (t < 256) ? sqp[t] : 0.0f;
#pragma unroll
  for (int o = 32; o > 0; o >>= 1) {
    term += __shfl_xor(term, o, 64);
    sq += __shfl_xor(sq, o, 64);
  }
  if ((t & 63) == 0) {
    red[t >> 6] = term;
    red2[t >> 6] = sq;
  }
  __syncthreads();
  if (t < 16) {
    float v = red[t];
    float s2 = red2[t];
#pragma unroll
    for (int o = 8; o > 0; o >>= 1) {
      v += __shfl_xor(v, o, 64);
      s2 += __shfl_xor(s2, o, 64);
    }
    if (t == 0) {
      float ppl = __expf(-v);
      float cbl = s2 * INV_ELEMS;
      out[O_LOSS] = cbl + 0.25f * cbl;
      out[O_CBL] = cbl;
      out[O_CML] = cbl;
      out[O_PPL] = ppl;
    }
  }
}

// ---------------------------------------------------------------------------
extern "C" void kernel_launch(void* const* d_in, const int* in_sizes, int n_in,
                              void* d_out, int out_size, void* d_ws,
                              size_t ws_size, hipStream_t stream) {
  const float* z = (const float*)d_in[0];
  const float* cb = (const float*)d_in[1];
  float* ws = (float*)d_ws;
  float* cn = ws;
  float* counts = ws + 1024;
  float* susum = ws + 2048;
  float* sqp = ws + 3072;
  float* cn2f = ws + 3328;
  short* chA = (short*)(ws + 4352);
  short* clA = (short*)(ws + 37120);
  float* ctA = ws + 69888;
  int* wl = (int*)(ws + 200960);
  float* out = (float*)d_out;

  hipMemsetAsync(counts, 0, (1024 + 1024 + 256) * sizeof(float), stream);
  hipMemsetAsync(wl, 0, sizeof(int), stream);

  vq_prep<<<256, 256, 0, stream>>>(cb, chA, clA, cn, cn2f);
  vq_p1<<<1024, 512, 0, stream>>>(z, chA, clA, cn2f, out, ctA, wl);
  vq_count<<<64, 256, 0, stream>>>(out + O_IDX, counts);
  vq_p2<<<2048, 256, 0, stream>>>((const short*)out, chA, clA, cn2f, ctA,
                                  susum);
  vq_rescan<<<256, 256, 0, stream>>>(z, cb, cn, out, counts, wl);
  vq_epi<<<N * 16 / 2048, 256, 0, stream>>>(z, cb, out + O_IDX, out + O_QST,
                                            sqp);
  vq_final<<<1, 1024, 0, stream>>>(counts, susum, sqp, out);
}

// Round 10
// 284.321 us; speedup vs baseline: 1.1505x; 1.1505x over previous
//
#include <hip/hip_runtime.h>

constexpr int K = 1024;        // num codes
constexpr int D = 64;          // dim
constexpr int N = 131072;      // 32*4096 points
constexpr float INV_N = 1.0f / 131072.0f;
constexpr float INV_ELEMS = 1.0f / 8388608.0f;  // N*D
constexpr float LOG2E = 1.4426950408889634f;
constexpr float DELTA = 0.0072f;  // refine margin in log2e-scaled units

// Output layout (flat float32, return order)
constexpr size_t O_QST  = 0;          // [N*D] quantized_st
constexpr size_t O_LOSS = 8388608;    // [1]
constexpr size_t O_IDX  = 8388609;    // [N]
constexpr size_t O_CBL  = 8519681;    // [1]
constexpr size_t O_CML  = 8519682;    // [1]
constexpr size_t O_PPL  = 8519683;    // [1]
constexpr size_t O_USG  = 8519684;    // [1024]
constexpr size_t O_SU   = 8520708;    // [1024]

// Workspace (float offsets):
//  [0,1024)       cn    raw fp32 codebook norms (rescan exact pass)
//  [1024,2048)    counts
//  [2048,3072)    susum
//  [3072,3328)    sqp
//  [3328,4352)    cn2f  cn * log2e (fp32, acc-init)
//  [4352,37120)   chA   bf16 hi split of codebook*log2e, frag layout
//  [37120,69888)  clA   bf16 lo split
//  [69888,200960) ctA   per-point ct2 = m - log2(Z)
//  [200960,332032) worklist: [0]=int count, [1..]=int point ids (cap 131071)

// qst slots double as z-frag storage between p1 and epi:
// tile t (32 points): shorts base = t*4096; hi frag at (ks*64+lane)*8,
// lo frag at 2048 + (ks*64+lane)*8.  Element (point=lane&31,
// dim=16*ks+(lane>>5)*8+j) holds split of (-2*z).

typedef __attribute__((ext_vector_type(8))) short bf16x8;
typedef __attribute__((ext_vector_type(16))) float f32x16;
typedef __attribute__((ext_vector_type(4))) float f32x4;  // nontemporal-ok

__device__ inline unsigned short f2bf(float f) {  // RTNE fp32->bf16
  unsigned u = __float_as_uint(f);
  return (unsigned short)((u + 0x7FFF + ((u >> 16) & 1)) >> 16);
}
__device__ inline float bf2f(unsigned short h) {
  return __uint_as_float(((unsigned)h) << 16);
}
__device__ inline float fexp2(float x) {  // raw v_exp_f32 (args <= 0 here)
  return __builtin_amdgcn_exp2f(x);
}
__device__ inline float fmed3(float a, float b, float c) {
  return __builtin_amdgcn_fmed3f(a, b, c);
}
__device__ inline bf16x8 negbf8(bf16x8 v) {  // flip sign of 8 packed bf16
  union { bf16x8 s; uint4 u; } x;
  x.s = v;
  x.u.x ^= 0x80008000u; x.u.y ^= 0x80008000u;
  x.u.z ^= 0x80008000u; x.u.w ^= 0x80008000u;
  return x.s;
}

// ---------------------------------------------------------------------------
// Codebook*log2e -> bf16 hi/lo frags + raw & scaled norms.
// Each 64-thread wave owns exactly one code row (gid>>6 uniform per wave).
__global__ __launch_bounds__(256) void vq_prep(const float* __restrict__ cb,
                                               short* __restrict__ chA,
                                               short* __restrict__ clA,
                                               float* __restrict__ cn,
                                               float* __restrict__ cn2f) {
  const int gid = blockIdx.x * 256 + threadIdx.x;  // 65536
  const int c = gid >> 6, d = gid & 63;
  float raw = cb[gid];
  float v = raw * LOG2E;
  unsigned short h = f2bf(v);
  unsigned short l = f2bf(v - bf2f(h));
  const int tile = c >> 5, ks = d >> 4, hff = (d >> 3) & 1, j = d & 7;
  const int lane = hff * 32 + (c & 31);
  const size_t off = ((size_t)((tile * 4 + ks) * 64 + lane)) * 8 + j;
  chA[off] = (short)h;
  clA[off] = (short)l;
  // norm reduction across the wave (one code per wave)
  float s = raw * raw;
#pragma unroll
  for (int o = 32; o > 0; o >>= 1) s += __shfl_xor(s, o, 64);
  if (d == 0) {
    cn[c] = s;
    cn2f[c] = s * LOG2E;
  }
}

// ---------------------------------------------------------------------------
// Pass 1, split-K: 8-wave blocks; wave pair shares a 32-point tile, each wave
// covers 512 codes (16 tiles).  Partials merge through LDS.
// launch_bounds(512,6): VGPR budget ~85 (r9 lesson: (512,8)'s 64-VGPR budget
// forced spills -- WRITE_SIZE doubled, both pipes idled).  3 blocks/CU x 8
// waves = 24 waves/CU, 1.5x the r7 occupancy, spill-free.
// Single 12-deep MFMA acc chain, med3 (min,secmin) tree, no per-point atomics.
__global__ __launch_bounds__(512, 6) void vq_p1(
    const float* __restrict__ z, const short* __restrict__ chA,
    const short* __restrict__ clA, const float* __restrict__ cn2f,
    float* __restrict__ out, float* __restrict__ ctA,
    int* __restrict__ wl) {
  __shared__ float Lm[8][32], LZ[8][32], Lb2[8][32];
  __shared__ int Lbi[8][32];
  const int tid = threadIdx.x;
  const int lane = tid & 63;
  const int w = tid >> 6;        // 0..7
  const int pair = w >> 1;       // 0..3: point tile within block
  const int half = w & 1;        // 0: codes 0-511, 1: codes 512-1023
  const int W = blockIdx.x * 4 + pair;
  const int i0 = W * 32;
  const int col = lane & 31;
  const int hf = lane >> 5;

  // convert this tile's z -> -2z hi/lo frags (both waves of the pair compute;
  // z rows are L1/L2/L3-shared).  Only half==0 stores them for p2.
  bf16x8 zh[4], zl[4];
  const float* zr = z + (size_t)(i0 + col) * 64 + hf * 8;
#pragma unroll
  for (int ks = 0; ks < 4; ks++) {
    float4 a = *(const float4*)(zr + ks * 16);
    float4 b = *(const float4*)(zr + ks * 16 + 4);
    float vv[8] = {a.x, a.y, a.z, a.w, b.x, b.y, b.z, b.w};
#pragma unroll
    for (int j = 0; j < 8; j++) {
      float vm = -2.0f * vv[j];
      unsigned short h = f2bf(vm);
      zh[ks][j] = (short)h;
      zl[ks][j] = (short)f2bf(vm - bf2f(h));
    }
  }
  if (half == 0) {
    short* base = (short*)out + (size_t)W * 4096;  // O_QST == 0
#pragma unroll
    for (int ks = 0; ks < 4; ks++) {
      *(bf16x8*)(base + (ks * 64 + lane) * 8) = zh[ks];
      *(bf16x8*)(base + 2048 + (ks * 64 + lane) * 8) = zl[ks];
    }
  }

  float b1 = 3.0e38f, b2 = 3.0e38f, Z = 0.0f;
  int bi = 0;

  for (int t = 0; t < 16; t++) {
    const int tt = half * 16 + t;  // this wave's code tile
    // acc init = cn2 of this tile's 16 row-codes (exact fp32 affine)
    float4 cniv[4];
#pragma unroll
    for (int q = 0; q < 4; q++)
      cniv[q] = *(const float4*)(cn2f + tt * 32 + 8 * q + 4 * hf);
    f32x16 acc;
#pragma unroll
    for (int r = 0; r < 16; r++)
      acc[r] = ((const float*)&cniv[r >> 2])[r & 3];
    const short* ch = chA + ((size_t)(tt * 4) * 64 + lane) * 8;
    const short* cl = clA + ((size_t)(tt * 4) * 64 + lane) * 8;
#pragma unroll
    for (int ks = 0; ks < 4; ks++) {
      bf16x8 Ah = *(const bf16x8*)(ch + ks * 512);
      bf16x8 Al = *(const bf16x8*)(cl + ks * 512);
      acc = __builtin_amdgcn_mfma_f32_32x32x16_bf16(Ah, zh[ks], acc, 0, 0, 0);
      acc = __builtin_amdgcn_mfma_f32_32x32x16_bf16(Ah, zl[ks], acc, 0, 0, 0);
      acc = __builtin_amdgcn_mfma_f32_32x32x16_bf16(Al, zh[ks], acc, 0, 0, 0);
    }
    // (min, secmin) merge tree with med3 merges.  Sorted pairs (a1<=a2),
    // (b1<=b2): min = min(a1,b1), sec = med3(a1, b1, min(a2,b2)).
    float pm[8], px[8];
#pragma unroll
    for (int r = 0; r < 8; r++) {
      pm[r] = fminf(acc[2 * r], acc[2 * r + 1]);
      px[r] = fmaxf(acc[2 * r], acc[2 * r + 1]);
    }
    float qm[4], qx[4];
#pragma unroll
    for (int r = 0; r < 4; r++) {
      qm[r] = fminf(pm[2 * r], pm[2 * r + 1]);
      qx[r] = fmed3(pm[2 * r], pm[2 * r + 1], fminf(px[2 * r], px[2 * r + 1]));
    }
    float rm0 = fminf(qm[0], qm[1]);
    float rx0 = fmed3(qm[0], qm[1], fminf(qx[0], qx[1]));
    float rm1 = fminf(qm[2], qm[3]);
    float rx1 = fmed3(qm[2], qm[3], fminf(qx[2], qx[3]));
    float cm = fminf(rm0, rm1);
    float cm2 = fmed3(rm0, rm1, fminf(rx0, rx1));
    // argmin of the tile (equality select; exact ties -> margin 0 -> rescan)
    int ti = 0;
#pragma unroll
    for (int r = 0; r < 16; r++)
      if (acc[r] == cm) ti = tt * 32 + (r & 3) + 8 * (r >> 2) + 4 * hf;
    // fold into running (b1, b2, bi); newm doubles as softmax max
    float newm = fminf(b1, cm);
    b2 = fmed3(b1, cm, fminf(b2, cm2));
    bi = (cm < b1) ? ti : bi;
    float zs = 0.0f;
#pragma unroll
    for (int r = 0; r < 16; r++) zs += fexp2(newm - acc[r]);
    Z = Z * fexp2(newm - b1) + zs;
    b1 = newm;
  }
  // intra-wave merge of the two hf halves
  float m2 = __shfl_xor(b1, 32, 64);
  float Z2 = __shfl_xor(Z, 32, 64);
  float b2o = __shfl_xor(b2, 32, 64);
  int bio = __shfl_xor(bi, 32, 64);
  float Mw = fminf(b1, m2);
  float Zw = Z * fexp2(Mw - b1) + Z2 * fexp2(Mw - m2);
  bool takeh = (m2 < b1) || (m2 == b1 && bio < bi);
  float g2w = fminf(fmaxf(b1, m2), fminf(b2, b2o));
  int biw = takeh ? bio : bi;
  // inter-wave (code-half) merge through LDS
  if (hf == 0) {
    Lm[w][col] = Mw;
    LZ[w][col] = Zw;
    Lb2[w][col] = g2w;
    Lbi[w][col] = biw;
  }
  __syncthreads();
  if (half == 0 && hf == 0) {
    float mB = Lm[w ^ 1][col];
    float ZB = LZ[w ^ 1][col];
    float b2B = Lb2[w ^ 1][col];
    int biB = Lbi[w ^ 1][col];
    float M = fminf(Mw, mB);
    float Zt = Zw * fexp2(M - Mw) + ZB * fexp2(M - mB);
    // strict less: ties keep half 0 (lower code index) -- correct argmin
    int big = (mB < Mw) ? biB : biw;
    float g2 = fminf(fmaxf(Mw, mB), fminf(g2w, b2B));
    ctA[i0 + col] = M - __log2f(Zt);
    out[O_IDX + (size_t)(i0 + col)] = (float)big;
    if (g2 - M < DELTA) {  // runner-up within margin -> exact rescan
      int slot = atomicAdd(wl, 1);
      if (slot < 131071) wl[1 + slot] = i0 + col;
    }
  }
}

// ---------------------------------------------------------------------------
// Histogram of indices via LDS privatization: 64 blocks x 2048 points each.
// 131K LDS atomics + 64K global atomics (vs 131K scattered global atomics).
__global__ __launch_bounds__(256) void vq_count(
    const float* __restrict__ idxF, float* __restrict__ counts) {
  __shared__ int h[K];
  const int tid = threadIdx.x;
#pragma unroll
  for (int k = 0; k < K / 256; k++) h[tid + k * 256] = 0;
  __syncthreads();
  const int base = blockIdx.x * 2048 + tid;
#pragma unroll
  for (int k = 0; k < 8; k++) {
    int c = (int)idxF[base + k * 256];
    atomicAdd(&h[c], 1);
  }
  __syncthreads();
#pragma unroll
  for (int k = 0; k < K / 256; k++) {
    int v = h[tid + k * 256];
    if (v) atomicAdd(&counts[tid + k * 256], (float)v);
  }
}

// ---------------------------------------------------------------------------
// Pass 2: wave = 32 resident (negated) codes, streams prebuilt z A-frags.
// Single MFMA chain; acc init = ct2_i - cn2_j (exact fp32); su += 2^acc.
// 2048 blocks: 256 point-groups x 16 tiles.
__global__ __launch_bounds__(256, 4) void vq_p2(
    const short* __restrict__ zF, const short* __restrict__ chA,
    const short* __restrict__ clA, const float* __restrict__ cn2f,
    const float* __restrict__ ctA, float* __restrict__ susum) {
  const int lane = threadIdx.x & 63;
  const int wv = threadIdx.x >> 6;
  const int b = blockIdx.x;
  // XCD swizzle: all 8 blocks of one point-group on one XCD (L2 reuse)
  const int xcd = b & 7;
  const int sl = b >> 3;                 // 0..255
  const int pg = xcd * 32 + (sl >> 3);   // 0..255 point group (512 points)
  const int g = (sl & 7) * 4 + wv;       // 0..31 code tile
  const int col = lane & 31;
  const int hf = lane >> 5;

  // resident codebook B frags, negated (codebook is +c*log2e; we need -c)
  bf16x8 Bh[4], Bl[4];
  const short* ch = chA + ((size_t)(g * 4) * 64 + lane) * 8;
  const short* cl = clA + ((size_t)(g * 4) * 64 + lane) * 8;
#pragma unroll
  for (int ks = 0; ks < 4; ks++) {
    Bh[ks] = negbf8(*(const bf16x8*)(ch + ks * 512));
    Bl[ks] = negbf8(*(const bf16x8*)(cl + ks * 512));
  }
  const float cnv = cn2f[g * 32 + col];  // this lane's code norm (scaled)

  float su = 0.0f;
  for (int pt = 0; pt < 16; pt++) {
    const int T = pg * 16 + pt;
    const short* base = zF + (size_t)T * 4096;
    float4 ctv[4];
#pragma unroll
    for (int q = 0; q < 4; q++)
      ctv[q] = *(const float4*)(ctA + T * 32 + 8 * q + 4 * hf);
    f32x16 acc;
#pragma unroll
    for (int r = 0; r < 16; r++)
      acc[r] = ((const float*)&ctv[r >> 2])[r & 3] - cnv;
#pragma unroll
    for (int ks = 0; ks < 4; ks++) {
      bf16x8 Ah = *(const bf16x8*)(base + (ks * 64 + lane) * 8);
      bf16x8 Al = *(const bf16x8*)(base + 2048 + (ks * 64 + lane) * 8);
      acc = __builtin_amdgcn_mfma_f32_32x32x16_bf16(Ah, Bh[ks], acc, 0, 0, 0);
      acc = __builtin_amdgcn_mfma_f32_32x32x16_bf16(Ah, Bl[ks], acc, 0, 0, 0);
      acc = __builtin_amdgcn_mfma_f32_32x32x16_bf16(Al, Bh[ks], acc, 0, 0, 0);
    }
#pragma unroll
    for (int r = 0; r < 16; r++) su += fexp2(acc[r]);
  }
  su += __shfl_xor(su, 32, 64);
  if (hf == 0) atomicAdd(&susum[g * 32 + col], su);
}

// ---------------------------------------------------------------------------
// Exact fp32 rescan for flagged (ambiguous) points only. Wave per entry,
// grid-stride over the device worklist. Updates out[O_IDX] and fixes counts.
__global__ __launch_bounds__(256) void vq_rescan(
    const float* __restrict__ z, const float* __restrict__ cb,
    const float* __restrict__ cn, float* __restrict__ out,
    float* __restrict__ counts, const int* __restrict__ wl) {
  const int nr = min(wl[0], 131071);
  const int wv = blockIdx.x * 4 + (threadIdx.x >> 6);
  const int lane = threadIdx.x & 63;
  for (int e = wv; e < nr; e += gridDim.x * 4) {
    const int i = wl[1 + e];
    const float4* zi4 = (const float4*)(z + (size_t)i * 64);
    float4 zq[16];
#pragma unroll
    for (int k = 0; k < 16; k++) zq[k] = zi4[k];
    float best = 3.0e38f;
    int bidx = 0;
    for (int cc = 0; cc < 16; cc++) {
      int c = cc * 64 + lane;
      const float4* cr = (const float4*)(cb + (size_t)c * 64);
      float dot0 = 0.0f, dot1 = 0.0f;
#pragma unroll
      for (int k = 0; k < 16; k += 2) {
        float4 a = cr[k];
        float4 bq = cr[k + 1];
        dot0 += zq[k].x * a.x + zq[k].y * a.y + zq[k].z * a.z + zq[k].w * a.w;
        dot1 += zq[k + 1].x * bq.x + zq[k + 1].y * bq.y + zq[k + 1].z * bq.z +
                zq[k + 1].w * bq.w;
      }
      float s = cn[c] - 2.0f * (dot0 + dot1);
      if (s < best) { best = s; bidx = c; }
    }
#pragma unroll
    for (int o = 32; o > 0; o >>= 1) {
      float ob = __shfl_xor(best, o, 64);
      int oi = __shfl_xor(bidx, o, 64);
      if (ob < best || (ob == best && oi < bidx)) { best = ob; bidx = oi; }
    }
    if (lane == 0) {
      const int old = (int)out[O_IDX + (size_t)i];
      if (bidx != old) {
        out[O_IDX + (size_t)i] = (float)bidx;
        atomicAdd(&counts[old], -1.0f);
        atomicAdd(&counts[bidx], 1.0f);
      }
    }
  }
}

// ---------------------------------------------------------------------------
// Epilogue: 8 independent float4 chunks per thread, loads batch-issued by
// class (idx -> z -> cb) for MLP.  No LDS, no barrier, no per-point atomics:
// per-wave shuffle reduce + one sqp atomic per wave.  Nontemporal stores keep
// the 32 MB qst stream out of L2.
__global__ __launch_bounds__(256) void vq_epi(
    const float* __restrict__ z, const float* __restrict__ cb,
    const float* __restrict__ idxF, float* __restrict__ qst,
    float* __restrict__ sqp) {
  const int tid = threadIdx.x;
  const int base = blockIdx.x * 2048 + tid;  // 8 chunks strided by 256
  const int q = base & 15;                   // dim-chunk, uniform over k
  int bI[8];
#pragma unroll
  for (int k = 0; k < 8; k++) bI[k] = (int)idxF[(base + k * 256) >> 4];
  f32x4 zv[8];
#pragma unroll
  for (int k = 0; k < 8; k++)
    zv[k] = __builtin_nontemporal_load((const f32x4*)z + base + k * 256);
  f32x4 qv[8];
#pragma unroll
  for (int k = 0; k < 8; k++) qv[k] = ((const f32x4*)cb)[bI[k] * 16 + q];
  float sq = 0.0f;
#pragma unroll
  for (int k = 0; k < 8; k++) {
    f32x4 o = zv[k] + (qv[k] - zv[k]);
    __builtin_nontemporal_store(o, (f32x4*)qst + base + k * 256);
    f32x4 e = qv[k] - zv[k];
    sq += e.x * e.x + e.y * e.y + e.z * e.z + e.w * e.w;
  }
#pragma unroll
  for (int o2 = 32; o2 > 0; o2 >>= 1) sq += __shfl_xor(sq, o2, 64);
  if ((tid & 63) == 0)
    atomicAdd(&sqp[(blockIdx.x * 4 + (tid >> 6)) & 255], sq);
}

// ---------------------------------------------------------------------------
__global__ __launch_bounds__(1024) void vq_final(
    const float* __restrict__ counts, const float* __restrict__ susum,
    const float* __restrict__ sqp, float* __restrict__ out) {
  __shared__ float red[16];
  __shared__ float red2[16];
  const int t = threadIdx.x;
  float cnt = counts[t];
  float usage = cnt * INV_N;
  out[O_USG + t] = usage;
  out[O_SU + t] = susum[t] * INV_N;
  float term = usage * logf(usage + 1e-8f);
  float sq = (t < 256) ? sqp[t] : 0.0f;
#pragma unroll
  for (int o = 32; o > 0; o >>= 1) {
    term += __shfl_xor(term, o, 64);
    sq += __shfl_xor(sq, o, 64);
  }
  if ((t & 63) == 0) {
    red[t >> 6] = term;
    red2[t >> 6] = sq;
  }
  __syncthreads();
  if (t < 16) {
    float v = red[t];
    float s2 = red2[t];
#pragma unroll
    for (int o = 8; o > 0; o >>= 1) {
      v += __shfl_xor(v, o, 64);
      s2 += __shfl_xor(s2, o, 64);
    }
    if (t == 0) {
      float ppl = __expf(-v);
      float cbl = s2 * INV_ELEMS;
      out[O_LOSS] = cbl + 0.25f * cbl;
      out[O_CBL] = cbl;
      out[O_CML] = cbl;
      out[O_PPL] = ppl;
    }
  }
}

// ---------------------------------------------------------------------------
extern "C" void kernel_launch(void* const* d_in, const int* in_sizes, int n_in,
                              void* d_out, int out_size, void* d_ws,
                              size_t ws_size, hipStream_t stream) {
  const float* z = (const float*)d_in[0];
  const float* cb = (const float*)d_in[1];
  float* ws = (float*)d_ws;
  float* cn = ws;
  float* counts = ws + 1024;
  float* susum = ws + 2048;
  float* sqp = ws + 3072;
  float* cn2f = ws + 3328;
  short* chA = (short*)(ws + 4352);
  short* clA = (short*)(ws + 37120);
  float* ctA = ws + 69888;
  int* wl = (int*)(ws + 200960);
  float* out = (float*)d_out;

  hipMemsetAsync(counts, 0, (1024 + 1024 + 256) * sizeof(float), stream);
  hipMemsetAsync(wl, 0, sizeof(int), stream);

  vq_prep<<<256, 256, 0, stream>>>(cb, chA, clA, cn, cn2f);
  vq_p1<<<1024, 512, 0, stream>>>(z, chA, clA, cn2f, out, ctA, wl);
  vq_count<<<64, 256, 0, stream>>>(out + O_IDX, counts);
  vq_p2<<<2048, 256, 0, stream>>>((const short*)out, chA, clA, cn2f, ctA,
                                  susum);
  vq_rescan<<<256, 256, 0, stream>>>(z, cb, cn, out, counts, wl);
  vq_epi<<<N * 16 / 2048, 256, 0, stream>>>(z, cb, out + O_IDX, out + O_QST,
                                            sqp);
  vq_final<<<1, 1024, 0, stream>>>(counts, susum, sqp, out);
}

// Round 11
// 275.622 us; speedup vs baseline: 1.1868x; 1.0316x over previous
//
#include <hip/hip_runtime.h>

constexpr int K = 1024;        // num codes
constexpr int D = 64;          // dim
constexpr int N = 131072;      // 32*4096 points
constexpr float INV_N = 1.0f / 131072.0f;
constexpr float INV_ELEMS = 1.0f / 8388608.0f;  // N*D
constexpr float LOG2E = 1.4426950408889634f;
constexpr float DELTA = 0.0072f;  // refine margin in log2e-scaled units
constexpr float SHIFT = 92.332482616893656f;  // 64*log2(e): ct-shift so p2
// can skip the per-tile -cn subtraction; 2^(acc) stays in f32 range since
// prob<=1 bounds acc <= (cn-64)*log2e <= ~81.

// Output layout (flat float32, return order)
constexpr size_t O_QST  = 0;          // [N*D] quantized_st
constexpr size_t O_LOSS = 8388608;    // [1]
constexpr size_t O_IDX  = 8388609;    // [N]
constexpr size_t O_CBL  = 8519681;    // [1]
constexpr size_t O_CML  = 8519682;    // [1]
constexpr size_t O_PPL  = 8519683;    // [1]
constexpr size_t O_USG  = 8519684;    // [1024]
constexpr size_t O_SU   = 8520708;    // [1024]

// Workspace (float offsets):
//  [0,1024)       cn    raw fp32 codebook norms (rescan exact pass)
//  [1024,2048)    counts
//  [2048,3072)    susum
//  [3072,3328)    sqp
//  [3328,4352)    cn2f  cn * log2e (fp32, acc-init)
//  [4352,37120)   chA   bf16 hi split of codebook*log2e, frag layout
//  [37120,69888)  clA   bf16 lo split
//  [69888,200960) ctA   per-point ct2' = m - log2(Z) - SHIFT
//  [200960,332032) worklist: [0]=int count, [1..]=int point ids (cap 131071)

// qst slots double as z-frag storage between p1 and epi:
// tile t (32 points): shorts base = t*4096; hi frag at (ks*64+lane)*8,
// lo frag at 2048 + (ks*64+lane)*8.  Element (point=lane&31,
// dim=16*ks+(lane>>5)*8+j) holds split of (-2*z).

typedef __attribute__((ext_vector_type(8))) short bf16x8;
typedef __attribute__((ext_vector_type(16))) float f32x16;
typedef __attribute__((ext_vector_type(4))) float f32x4;  // nontemporal-ok

__device__ inline unsigned short f2bf(float f) {  // RTNE fp32->bf16
  unsigned u = __float_as_uint(f);
  return (unsigned short)((u + 0x7FFF + ((u >> 16) & 1)) >> 16);
}
__device__ inline float bf2f(unsigned short h) {
  return __uint_as_float(((unsigned)h) << 16);
}
__device__ inline float fexp2(float x) {  // raw v_exp_f32
  return __builtin_amdgcn_exp2f(x);
}
__device__ inline float fmed3(float a, float b, float c) {
  return __builtin_amdgcn_fmed3f(a, b, c);
}
__device__ inline bf16x8 negbf8(bf16x8 v) {  // flip sign of 8 packed bf16
  union { bf16x8 s; uint4 u; } x;
  x.s = v;
  x.u.x ^= 0x80008000u; x.u.y ^= 0x80008000u;
  x.u.z ^= 0x80008000u; x.u.w ^= 0x80008000u;
  return x.s;
}

// ---------------------------------------------------------------------------
// Codebook*log2e -> bf16 hi/lo frags + raw & scaled norms.
// Each 64-thread wave owns exactly one code row (gid>>6 uniform per wave).
__global__ __launch_bounds__(256) void vq_prep(const float* __restrict__ cb,
                                               short* __restrict__ chA,
                                               short* __restrict__ clA,
                                               float* __restrict__ cn,
                                               float* __restrict__ cn2f) {
  const int gid = blockIdx.x * 256 + threadIdx.x;  // 65536
  const int c = gid >> 6, d = gid & 63;
  float raw = cb[gid];
  float v = raw * LOG2E;
  unsigned short h = f2bf(v);
  unsigned short l = f2bf(v - bf2f(h));
  const int tile = c >> 5, ks = d >> 4, hff = (d >> 3) & 1, j = d & 7;
  const int lane = hff * 32 + (c & 31);
  const size_t off = ((size_t)((tile * 4 + ks) * 64 + lane)) * 8 + j;
  chA[off] = (short)h;
  clA[off] = (short)l;
  // norm reduction across the wave (one code per wave)
  float s = raw * raw;
#pragma unroll
  for (int o = 32; o > 0; o >>= 1) s += __shfl_xor(s, o, 64);
  if (d == 0) {
    cn[c] = s;
    cn2f[c] = s * LOG2E;
  }
}

// ---------------------------------------------------------------------------
// Pass 1: wave = 32 points x all 1024 codes (r7 structure; split-K reverted
// -- r10 showed occupancy 35->51% gives zero, so extra waves don't pay).
// NEW: 2-stage software pipeline -- tile t+1's 8 chA/clA loads issue before
// tile t's MFMA+VALU block, covering the ~200cy L2 latency the un-unrolled
// loop ate at every s_waitcnt.  lb(256,3) gives the double buffer VGPR room
// (r9 lesson: a tight bound forces spills, which cost far more than occ).
__global__ __launch_bounds__(256, 3) void vq_p1(
    const float* __restrict__ z, const short* __restrict__ chA,
    const short* __restrict__ clA, const float* __restrict__ cn2f,
    float* __restrict__ out, float* __restrict__ ctA,
    int* __restrict__ wl) {
  const int lane = threadIdx.x & 63;
  const int W = blockIdx.x * 4 + (threadIdx.x >> 6);
  const int i0 = W * 32;
  const int col = lane & 31;
  const int hf = lane >> 5;

  // convert this tile's z -> -2z hi/lo frags (B-operand layout), store for p2
  bf16x8 zh[4], zl[4];
  const float* zr = z + (size_t)(i0 + col) * 64 + hf * 8;
#pragma unroll
  for (int ks = 0; ks < 4; ks++) {
    float4 a = *(const float4*)(zr + ks * 16);
    float4 b = *(const float4*)(zr + ks * 16 + 4);
    float vv[8] = {a.x, a.y, a.z, a.w, b.x, b.y, b.z, b.w};
#pragma unroll
    for (int j = 0; j < 8; j++) {
      float vm = -2.0f * vv[j];
      unsigned short h = f2bf(vm);
      zh[ks][j] = (short)h;
      zl[ks][j] = (short)f2bf(vm - bf2f(h));
    }
  }
  {
    short* base = (short*)out + (size_t)W * 4096;  // O_QST == 0
#pragma unroll
    for (int ks = 0; ks < 4; ks++) {
      *(bf16x8*)(base + (ks * 64 + lane) * 8) = zh[ks];
      *(bf16x8*)(base + 2048 + (ks * 64 + lane) * 8) = zl[ks];
    }
  }

  float b1 = 3.0e38f, b2 = 3.0e38f, Z = 0.0f;
  int bi = 0;

  // process one code tile tt with frags AH/AL; updates running state
  auto step = [&](int tt, const bf16x8* AH, const bf16x8* AL) {
    float4 cniv[4];
#pragma unroll
    for (int q = 0; q < 4; q++)
      cniv[q] = *(const float4*)(cn2f + tt * 32 + 8 * q + 4 * hf);
    f32x16 acc;
#pragma unroll
    for (int r = 0; r < 16; r++)
      acc[r] = ((const float*)&cniv[r >> 2])[r & 3];
#pragma unroll
    for (int ks = 0; ks < 4; ks++) {
      acc = __builtin_amdgcn_mfma_f32_32x32x16_bf16(AH[ks], zh[ks], acc, 0, 0, 0);
      acc = __builtin_amdgcn_mfma_f32_32x32x16_bf16(AH[ks], zl[ks], acc, 0, 0, 0);
      acc = __builtin_amdgcn_mfma_f32_32x32x16_bf16(AL[ks], zh[ks], acc, 0, 0, 0);
    }
    // (min, secmin) merge tree with med3 merges.
    float pm[8], px[8];
#pragma unroll
    for (int r = 0; r < 8; r++) {
      pm[r] = fminf(acc[2 * r], acc[2 * r + 1]);
      px[r] = fmaxf(acc[2 * r], acc[2 * r + 1]);
    }
    float qm[4], qx[4];
#pragma unroll
    for (int r = 0; r < 4; r++) {
      qm[r] = fminf(pm[2 * r], pm[2 * r + 1]);
      qx[r] = fmed3(pm[2 * r], pm[2 * r + 1], fminf(px[2 * r], px[2 * r + 1]));
    }
    float rm0 = fminf(qm[0], qm[1]);
    float rx0 = fmed3(qm[0], qm[1], fminf(qx[0], qx[1]));
    float rm1 = fminf(qm[2], qm[3]);
    float rx1 = fmed3(qm[2], qm[3], fminf(qx[2], qx[3]));
    float cm = fminf(rm0, rm1);
    float cm2 = fmed3(rm0, rm1, fminf(rx0, rx1));
    // argmin of the tile (equality select; exact ties -> margin 0 -> rescan)
    int ti = 0;
#pragma unroll
    for (int r = 0; r < 16; r++)
      if (acc[r] == cm) ti = tt * 32 + (r & 3) + 8 * (r >> 2) + 4 * hf;
    float newm = fminf(b1, cm);
    b2 = fmed3(b1, cm, fminf(b2, cm2));
    bi = (cm < b1) ? ti : bi;
    float zs0 = 0.0f, zs1 = 0.0f;  // split dependent add chain
#pragma unroll
    for (int r = 0; r < 16; r += 2) {
      zs0 += fexp2(newm - acc[r]);
      zs1 += fexp2(newm - acc[r + 1]);
    }
    Z = Z * fexp2(newm - b1) + (zs0 + zs1);
    b1 = newm;
  };

  // 2-stage ping-pong pipeline over the 32 code tiles
  bf16x8 A0h[4], A0l[4], A1h[4], A1l[4];
#pragma unroll
  for (int ks = 0; ks < 4; ks++) {
    A0h[ks] = *(const bf16x8*)(chA + (size_t)lane * 8 + ks * 512);
    A0l[ks] = *(const bf16x8*)(clA + (size_t)lane * 8 + ks * 512);
  }
  for (int t = 0; t < 32; t += 2) {
    const size_t o1 = (size_t)(t + 1) * 2048 + lane * 8;
#pragma unroll
    for (int ks = 0; ks < 4; ks++) {
      A1h[ks] = *(const bf16x8*)(chA + o1 + ks * 512);
      A1l[ks] = *(const bf16x8*)(clA + o1 + ks * 512);
    }
    step(t, A0h, A0l);
    const size_t o2 = (size_t)((t + 2) & 31) * 2048 + lane * 8;  // wraps: harmless re-read
#pragma unroll
    for (int ks = 0; ks < 4; ks++) {
      A0h[ks] = *(const bf16x8*)(chA + o2 + ks * 512);
      A0l[ks] = *(const bf16x8*)(clA + o2 + ks * 512);
    }
    step(t + 1, A1h, A1l);
  }

  // merge the two half-wave partials
  float m2 = __shfl_xor(b1, 32, 64);
  float Z2 = __shfl_xor(Z, 32, 64);
  float b1o = m2;
  float b2o = __shfl_xor(b2, 32, 64);
  int bio = __shfl_xor(bi, 32, 64);
  float M = fminf(b1, m2);
  float Zt = Z * fexp2(M - b1) + Z2 * fexp2(M - m2);
  bool take = (b1o < b1) || (b1o == b1 && bio < bi);
  float g2 = fminf(fmaxf(b1, b1o), fminf(b2, b2o));
  int big = take ? bio : bi;
  if (hf == 0) {
    ctA[i0 + col] = M - __log2f(Zt) - SHIFT;
    out[O_IDX + (size_t)(i0 + col)] = (float)big;
    if (g2 - M < DELTA) {  // runner-up within margin -> exact rescan
      int slot = atomicAdd(wl, 1);
      if (slot < 131071) wl[1 + slot] = i0 + col;
    }
  }
}

// ---------------------------------------------------------------------------
// Histogram of indices via LDS privatization: 64 blocks x 2048 points each.
__global__ __launch_bounds__(256) void vq_count(
    const float* __restrict__ idxF, float* __restrict__ counts) {
  __shared__ int h[K];
  const int tid = threadIdx.x;
#pragma unroll
  for (int k = 0; k < K / 256; k++) h[tid + k * 256] = 0;
  __syncthreads();
  const int base = blockIdx.x * 2048 + tid;
#pragma unroll
  for (int k = 0; k < 8; k++) {
    int c = (int)idxF[base + k * 256];
    atomicAdd(&h[c], 1);
  }
  __syncthreads();
#pragma unroll
  for (int k = 0; k < K / 256; k++) {
    int v = h[tid + k * 256];
    if (v) atomicAdd(&counts[tid + k * 256], (float)v);
  }
}

// ---------------------------------------------------------------------------
// Pass 2: wave = 32 resident (negated) codes, streams prebuilt z A-frags.
// SHIFT fold: acc init = ct' alone (ct' already carries -SHIFT); the -cn*L
// term is applied ONCE per wave at the end as escale = 2^(SHIFT - cn*L).
// Deletes 16 v_sub per tile.  su chain split for ILP.
__global__ __launch_bounds__(256, 4) void vq_p2(
    const short* __restrict__ zF, const short* __restrict__ chA,
    const short* __restrict__ clA, const float* __restrict__ cn2f,
    const float* __restrict__ ctA, float* __restrict__ susum) {
  const int lane = threadIdx.x & 63;
  const int wv = threadIdx.x >> 6;
  const int b = blockIdx.x;
  // XCD swizzle: all 8 blocks of one point-group on one XCD (L2 reuse)
  const int xcd = b & 7;
  const int sl = b >> 3;                 // 0..255
  const int pg = xcd * 32 + (sl >> 3);   // 0..255 point group
  const int g = (sl & 7) * 4 + wv;       // 0..31 code tile
  const int col = lane & 31;
  const int hf = lane >> 5;

  // resident codebook B frags, negated (codebook is +c*log2e; we need -c)
  bf16x8 Bh[4], Bl[4];
  const short* ch = chA + ((size_t)(g * 4) * 64 + lane) * 8;
  const short* cl = clA + ((size_t)(g * 4) * 64 + lane) * 8;
#pragma unroll
  for (int ks = 0; ks < 4; ks++) {
    Bh[ks] = negbf8(*(const bf16x8*)(ch + ks * 512));
    Bl[ks] = negbf8(*(const bf16x8*)(cl + ks * 512));
  }
  const float cnv = cn2f[g * 32 + col];     // this lane's code norm (scaled)
  const float escale = fexp2(SHIFT - cnv);  // applied once at retire

  float su0 = 0.0f, su1 = 0.0f;
  for (int pt = 0; pt < 16; pt++) {
    const int T = pg * 16 + pt;
    const short* base = zF + (size_t)T * 4096;
    float4 ctv[4];
#pragma unroll
    for (int q = 0; q < 4; q++)
      ctv[q] = *(const float4*)(ctA + T * 32 + 8 * q + 4 * hf);
    f32x16 acc;
#pragma unroll
    for (int r = 0; r < 16; r++)
      acc[r] = ((const float*)&ctv[r >> 2])[r & 3];
#pragma unroll
    for (int ks = 0; ks < 4; ks++) {
      bf16x8 Ah = *(const bf16x8*)(base + (ks * 64 + lane) * 8);
      bf16x8 Al = *(const bf16x8*)(base + 2048 + (ks * 64 + lane) * 8);
      acc = __builtin_amdgcn_mfma_f32_32x32x16_bf16(Ah, Bh[ks], acc, 0, 0, 0);
      acc = __builtin_amdgcn_mfma_f32_32x32x16_bf16(Ah, Bl[ks], acc, 0, 0, 0);
      acc = __builtin_amdgcn_mfma_f32_32x32x16_bf16(Al, Bh[ks], acc, 0, 0, 0);
    }
#pragma unroll
    for (int r = 0; r < 16; r += 2) {
      su0 += fexp2(acc[r]);
      su1 += fexp2(acc[r + 1]);
    }
  }
  float su = (su0 + su1) * escale;
  su += __shfl_xor(su, 32, 64);
  if (hf == 0) atomicAdd(&susum[g * 32 + col], su);
}

// ---------------------------------------------------------------------------
// Exact fp32 rescan for flagged (ambiguous) points only. Wave per entry,
// grid-stride over the device worklist. Updates out[O_IDX] and fixes counts.
__global__ __launch_bounds__(256) void vq_rescan(
    const float* __restrict__ z, const float* __restrict__ cb,
    const float* __restrict__ cn, float* __restrict__ out,
    float* __restrict__ counts, const int* __restrict__ wl) {
  const int nr = min(wl[0], 131071);
  const int wv = blockIdx.x * 4 + (threadIdx.x >> 6);
  const int lane = threadIdx.x & 63;
  for (int e = wv; e < nr; e += gridDim.x * 4) {
    const int i = wl[1 + e];
    const float4* zi4 = (const float4*)(z + (size_t)i * 64);
    float4 zq[16];
#pragma unroll
    for (int k = 0; k < 16; k++) zq[k] = zi4[k];
    float best = 3.0e38f;
    int bidx = 0;
    for (int cc = 0; cc < 16; cc++) {
      int c = cc * 64 + lane;
      const float4* cr = (const float4*)(cb + (size_t)c * 64);
      float dot0 = 0.0f, dot1 = 0.0f;
#pragma unroll
      for (int k = 0; k < 16; k += 2) {
        float4 a = cr[k];
        float4 bq = cr[k + 1];
        dot0 += zq[k].x * a.x + zq[k].y * a.y + zq[k].z * a.z + zq[k].w * a.w;
        dot1 += zq[k + 1].x * bq.x + zq[k + 1].y * bq.y + zq[k + 1].z * bq.z +
                zq[k + 1].w * bq.w;
      }
      float s = cn[c] - 2.0f * (dot0 + dot1);
      if (s < best) { best = s; bidx = c; }
    }
#pragma unroll
    for (int o = 32; o > 0; o >>= 1) {
      float ob = __shfl_xor(best, o, 64);
      int oi = __shfl_xor(bidx, o, 64);
      if (ob < best || (ob == best && oi < bidx)) { best = ob; bidx = oi; }
    }
    if (lane == 0) {
      const int old = (int)out[O_IDX + (size_t)i];
      if (bidx != old) {
        out[O_IDX + (size_t)i] = (float)bidx;
        atomicAdd(&counts[old], -1.0f);
        atomicAdd(&counts[bidx], 1.0f);
      }
    }
  }
}

// ---------------------------------------------------------------------------
// Epilogue: 8 independent float4 chunks per thread, loads batch-issued by
// class (idx -> z -> cb) for MLP.  Per-wave shuffle reduce + one sqp atomic
// per wave.  Nontemporal streams keep the 32 MB qst write out of L2.
__global__ __launch_bounds__(256) void vq_epi(
    const float* __restrict__ z, const float* __restrict__ cb,
    const float* __restrict__ idxF, float* __restrict__ qst,
    float* __restrict__ sqp) {
  const int tid = threadIdx.x;
  const int base = blockIdx.x * 2048 + tid;  // 8 chunks strided by 256
  const int q = base & 15;                   // dim-chunk, uniform over k
  int bI[8];
#pragma unroll
  for (int k = 0; k < 8; k++) bI[k] = (int)idxF[(base + k * 256) >> 4];
  f32x4 zv[8];
#pragma unroll
  for (int k = 0; k < 8; k++)
    zv[k] = __builtin_nontemporal_load((const f32x4*)z + base + k * 256);
  f32x4 qv[8];
#pragma unroll
  for (int k = 0; k < 8; k++) qv[k] = ((const f32x4*)cb)[bI[k] * 16 + q];
  float sq = 0.0f;
#pragma unroll
  for (int k = 0; k < 8; k++) {
    f32x4 o = zv[k] + (qv[k] - zv[k]);
    __builtin_nontemporal_store(o, (f32x4*)qst + base + k * 256);
    f32x4 e = qv[k] - zv[k];
    sq += e.x * e.x + e.y * e.y + e.z * e.z + e.w * e.w;
  }
#pragma unroll
  for (int o2 = 32; o2 > 0; o2 >>= 1) sq += __shfl_xor(sq, o2, 64);
  if ((tid & 63) == 0)
    atomicAdd(&sqp[(blockIdx.x * 4 + (tid >> 6)) & 255], sq);
}

// ---------------------------------------------------------------------------
__global__ __launch_bounds__(1024) void vq_final(
    const float* __restrict__ counts, const float* __restrict__ susum,
    const float* __restrict__ sqp, float* __restrict__ out) {
  __shared__ float red[16];
  __shared__ float red2[16];
  const int t = threadIdx.x;
  float cnt = counts[t];
  float usage = cnt * INV_N;
  out[O_USG + t] = usage;
  out[O_SU + t] = susum[t] * INV_N;
  float term = usage * logf(usage + 1e-8f);
  float sq = (t < 256) ? sqp[t] : 0.0f;
#pragma unroll
  for (int o = 32; o > 0; o >>= 1) {
    term += __shfl_xor(term, o, 64);
    sq += __shfl_xor(sq, o, 64);
  }
  if ((t & 63) == 0) {
    red[t >> 6] = term;
    red2[t >> 6] = sq;
  }
  __syncthreads();
  if (t < 16) {
    float v = red[t];
    float s2 = red2[t];
#pragma unroll
    for (int o = 8; o > 0; o >>= 1) {
      v += __shfl_xor(v, o, 64);
      s2 += __shfl_xor(s2, o, 64);
    }
    if (t == 0) {
      float ppl = __expf(-v);
      float cbl = s2 * INV_ELEMS;
      out[O_LOSS] = cbl + 0.25f * cbl;
      out[O_CBL] = cbl;
      out[O_CML] = cbl;
      out[O_PPL] = ppl;
    }
  }
}

// ---------------------------------------------------------------------------
extern "C" void kernel_launch(void* const* d_in, const int* in_sizes, int n_in,
                              void* d_out, int out_size, void* d_ws,
                              size_t ws_size, hipStream_t stream) {
  const float* z = (const float*)d_in[0];
  const float* cb = (const float*)d_in[1];
  float* ws = (float*)d_ws;
  float* cn = ws;
  float* counts = ws + 1024;
  float* susum = ws + 2048;
  float* sqp = ws + 3072;
  float* cn2f = ws + 3328;
  short* chA = (short*)(ws + 4352);
  short* clA = (short*)(ws + 37120);
  float* ctA = ws + 69888;
  int* wl = (int*)(ws + 200960);
  float* out = (float*)d_out;

  hipMemsetAsync(counts, 0, (1024 + 1024 + 256) * sizeof(float), stream);
  hipMemsetAsync(wl, 0, sizeof(int), stream);

  vq_prep<<<256, 256, 0, stream>>>(cb, chA, clA, cn, cn2f);
  vq_p1<<<1024, 256, 0, stream>>>(z, chA, clA, cn2f, out, ctA, wl);
  vq_count<<<64, 256, 0, stream>>>(out + O_IDX, counts);
  vq_p2<<<2048, 256, 0, stream>>>((const short*)out, chA, clA, cn2f, ctA,
                                  susum);
  vq_rescan<<<256, 256, 0, stream>>>(z, cb, cn, out, counts, wl);
  vq_epi<<<N * 16 / 2048, 256, 0, stream>>>(z, cb, out + O_IDX, out + O_QST,
                                            sqp);
  vq_final<<<1, 1024, 0, stream>>>(counts, susum, sqp, out);
}